// Round 8
// baseline (346.328 us; speedup 1.0000x reference)
//
#include <hip/hip_runtime.h>

typedef unsigned int u32;
typedef __attribute__((ext_vector_type(4))) int i32x4;   // 16 i8 (A/B frag) or 4 i32 (C/D)

#define BM 256
#define BN 256
#define BKT 128   // K elements (i8) per K-tile: one LDS row = 128 B

__device__ __forceinline__ void gload16(const void* g, void* l) {
  __builtin_amdgcn_global_load_lds(
      (const __attribute__((address_space(1))) unsigned int*)g,
      (__attribute__((address_space(3))) unsigned int*)l, 16, 0, 0);
}

__device__ __forceinline__ u32 pack4_i8(float4 v, float scale) {
  const int a = (int)rintf(v.x / scale);
  const int b = (int)rintf(v.y / scale);
  const int c = (int)rintf(v.z / scale);
  const int d = (int)rintf(v.w / scale);
  return (u32)(a & 255) | (((u32)(b & 255)) << 8) |
         (((u32)(c & 255)) << 16) | (((u32)(d & 255)) << 24);
}

// ---------------- per-row fake-quant -> int8, single-pass (K==4096) ----------------
__global__ __launch_bounds__(256) void quant_rows4096_kernel(
    const float* __restrict__ src, u32* __restrict__ q,   // q: i8 rows packed as u32
    float* __restrict__ scales)
{
  const size_t row = blockIdx.x;
  const float4* __restrict__ p = (const float4*)(src + row * 4096);
  const int t = threadIdx.x;
  float4 v0 = p[t];
  float4 v1 = p[t + 256];
  float4 v2 = p[t + 512];
  float4 v3 = p[t + 768];
  float m = 0.0f;
  m = fmaxf(m, fmaxf(fmaxf(fabsf(v0.x), fabsf(v0.y)), fmaxf(fabsf(v0.z), fabsf(v0.w))));
  m = fmaxf(m, fmaxf(fmaxf(fabsf(v1.x), fabsf(v1.y)), fmaxf(fabsf(v1.z), fabsf(v1.w))));
  m = fmaxf(m, fmaxf(fmaxf(fabsf(v2.x), fabsf(v2.y)), fmaxf(fabsf(v2.z), fabsf(v2.w))));
  m = fmaxf(m, fmaxf(fmaxf(fabsf(v3.x), fabsf(v3.y)), fmaxf(fabsf(v3.z), fabsf(v3.w))));
  #pragma unroll
  for (int off = 32; off > 0; off >>= 1) m = fmaxf(m, __shfl_xor(m, off));
  __shared__ float wmax[4];
  if ((t & 63) == 0) wmax[t >> 6] = m;
  __syncthreads();
  m = fmaxf(fmaxf(wmax[0], wmax[1]), fmaxf(wmax[2], wmax[3]));
  const float scale = fmaxf(m, 1e-5f) * (1.0f / 127.0f);
  if (t == 0) scales[row] = scale;
  u32* __restrict__ qp = q + row * 1024;
  qp[t]       = pack4_i8(v0, scale);
  qp[t + 256] = pack4_i8(v1, scale);
  qp[t + 512] = pack4_i8(v2, scale);
  qp[t + 768] = pack4_i8(v3, scale);
}

// generic fallback (any K multiple of 4)
__global__ __launch_bounds__(256) void quant_rows_kernel(
    const float* __restrict__ src, u32* __restrict__ q,
    float* __restrict__ scales, int K)
{
  const size_t row = blockIdx.x;
  const float* __restrict__ p = src + row * (size_t)K;
  const int t = threadIdx.x;
  const int nv = K >> 2;
  float m = 0.0f;
  for (int i = t; i < nv; i += 256) {
    float4 v = ((const float4*)p)[i];
    m = fmaxf(m, fmaxf(fmaxf(fabsf(v.x), fabsf(v.y)),
                       fmaxf(fabsf(v.z), fabsf(v.w))));
  }
  #pragma unroll
  for (int off = 32; off > 0; off >>= 1) m = fmaxf(m, __shfl_xor(m, off));
  __shared__ float wmax[4];
  if ((t & 63) == 0) wmax[t >> 6] = m;
  __syncthreads();
  m = fmaxf(fmaxf(wmax[0], wmax[1]), fmaxf(wmax[2], wmax[3]));
  const float scale = fmaxf(m, 1e-5f) * (1.0f / 127.0f);
  if (t == 0) scales[row] = scale;
  u32* __restrict__ qp = q + row * ((size_t)K >> 2);
  for (int i = t; i < nv; i += 256) {
    float4 v = ((const float4*)p)[i];
    qp[i] = pack4_i8(v, scale);
  }
}

// ------- 256x256 8-wave i8 GEMM, BK=128: A via LDS (swizzled), B direct global->reg -------
// C = Aq(MxK) * Bq(NxK)^T, i8 inputs, exact i32 accumulate via mfma_i32_16x16x64_i8.
// LDS: 2 slots x (A 256x128B) = 64 KiB. A swizzle: LDS (row, slot16) holds global
// (row, slot16 ^ (row&7)); applied on the global SOURCE at staging + on ds_read addr.
// B fragments: the unswizzled global address of what the old LDS path delivered —
// Bq[(bcol+wc*64+j*16+l16)*K + kt*128 + (ks*4+g4)*16] — loaded straight to VGPRs,
// one K-tile ahead, parity-alternating register sets (no moves).
// Sync: 4 windows/K-tile {reads(4 ds) -> BAR -> 16 MFMA -> BAR}; one vmcnt(0) at W4
// (12 loads issued >=2 windows earlier). WAR on LDS slot reuse protected by the
// same barrier argument as R6 (reads of a slot lgkm-complete before their MFMA,
// which precedes the barrier that releases re-staging).
__global__ __launch_bounds__(512, 2) void gemm_bt_kernel(
    const signed char* __restrict__ Aq, const signed char* __restrict__ Bq,
    const float* __restrict__ sx, const float* __restrict__ sw,
    const float* __restrict__ bias, float* __restrict__ Y,
    unsigned int* __restrict__ rowmax, int M, int N, int K)
{
  __shared__ signed char lds[2][BM * 128];   // [slot][A], 128 B per row, 64 KiB total

  int bid = (int)blockIdx.x;
  const int nwg = (int)gridDim.x;
  if ((nwg & 7) == 0) {                 // bijective XCD swizzle
    const int cpx = nwg >> 3;
    bid = (bid & 7) * cpx + (bid >> 3);
  }
  const int ntile = N / BN;
  const size_t brow = (size_t)(bid / ntile) * BM;
  const size_t bcol = (size_t)(bid % ntile) * BN;

  const int t = threadIdx.x;
  const int lane = t & 63;
  const int wid = t >> 6;
  const int wr = wid >> 2, wc = wid & 3;       // 2(M) x 4(N) wave grid
  const int g4 = lane >> 4, l16 = lane & 15, l7 = lane & 7;

  const int aRow = wr * 128 + l16;             // + mh*64 + i*16
  const int col0 = ((g4) ^ l7) * 16;           // kk=0 swizzled 16B slot (byte offset)
  const int col1 = ((4 + g4) ^ l7) * 16;       // kk=1

  // A staging: thread covers row tr of each 64-row stripe and 16B slot ts,
  // pre-swizzled source slot so linear LDS dest ends up swizzled.
  const int tr = t >> 3, ts = t & 7;
  const int sslot = ts ^ (tr & 7);
  const signed char* srcA = Aq + (brow + tr) * (size_t)K + sslot * 16;
  const int dst = t * 16;                      // byte offset within 8 KiB stripe

  // B direct: row-major N x K i8 viewed as i32x4 (16B) units; row stride = K/16.
  const int kq = K >> 4;                       // i32x4 per row
  const i32x4* __restrict__ Bg = (const i32x4*)Bq + (bcol + wc * 64 + l16) * (size_t)kq;

  i32x4 acc0[4][4] = {};   // mh0 (rows wr*128 + 0..63), exact i32
  i32x4 acc1[4][4] = {};   // mh1 (rows wr*128 + 64..127)
  const int nK = K / BKT;

  i32x4 aA0, aA1, aA2, aA3;   // mh0 col0
  i32x4 aB0, aB1, aB2, aB3;   // mh0 col1
  i32x4 aC0, aC1, aC2, aC3;   // mh1 col0
  i32x4 aD0, aD1, aD2, aD3;   // mh1 col1
  // B fragment sets, parity-alternating (E = even tiles, O = odd tiles)
  i32x4 bEA0, bEA1, bEA2, bEA3, bEB0, bEB1, bEB2, bEB3;
  i32x4 bOA0, bOA1, bOA2, bOA3, bOB0, bOB1, bOB2, bOB3;

#define STA(S, R, TT) gload16(srcA + ((size_t)(R) * 64) * (size_t)K + (size_t)(TT) * BKT, \
                              &lds[S][(R) * 8192 + dst])
#define STAGEA(S, TT) do { STA(S, 0, TT); STA(S, 1, TT); STA(S, 2, TT); STA(S, 3, TT); } while (0)
#define BARS() do { asm volatile("" ::: "memory"); \
                    __builtin_amdgcn_s_barrier(); \
                    asm volatile("" ::: "memory"); } while (0)
#define VMWS(NN) asm volatile("s_waitcnt vmcnt(" #NN ")" ::: "memory")
#define RDA(P, S, MH, COL) do { \
    P##0 = *(const i32x4*)&lds[S][(aRow + (MH) * 64 +  0) * 128 + (COL)]; \
    P##1 = *(const i32x4*)&lds[S][(aRow + (MH) * 64 + 16) * 128 + (COL)]; \
    P##2 = *(const i32x4*)&lds[S][(aRow + (MH) * 64 + 32) * 128 + (COL)]; \
    P##3 = *(const i32x4*)&lds[S][(aRow + (MH) * 64 + 48) * 128 + (COL)]; } while (0)
// Load B frags for tile TT into set P (PA = k-slot0, PB = k-slot1): 8 x dwordx4.
#define LOADB(PA, PB, TT) do { \
    PA##0 = Bg[ 0 * kq + (TT) * 8 +     g4]; \
    PA##1 = Bg[16 * kq + (TT) * 8 +     g4]; \
    PA##2 = Bg[32 * kq + (TT) * 8 +     g4]; \
    PA##3 = Bg[48 * kq + (TT) * 8 +     g4]; \
    PB##0 = Bg[ 0 * kq + (TT) * 8 + 4 + g4]; \
    PB##1 = Bg[16 * kq + (TT) * 8 + 4 + g4]; \
    PB##2 = Bg[32 * kq + (TT) * 8 + 4 + g4]; \
    PB##3 = Bg[48 * kq + (TT) * 8 + 4 + g4]; } while (0)
#define MF(ACC, A, B) do { \
    __builtin_amdgcn_s_setprio(1); \
    ACC[0][0] = __builtin_amdgcn_mfma_i32_16x16x64_i8(A##0, B##0, ACC[0][0], 0, 0, 0); \
    ACC[0][1] = __builtin_amdgcn_mfma_i32_16x16x64_i8(A##0, B##1, ACC[0][1], 0, 0, 0); \
    ACC[0][2] = __builtin_amdgcn_mfma_i32_16x16x64_i8(A##0, B##2, ACC[0][2], 0, 0, 0); \
    ACC[0][3] = __builtin_amdgcn_mfma_i32_16x16x64_i8(A##0, B##3, ACC[0][3], 0, 0, 0); \
    ACC[1][0] = __builtin_amdgcn_mfma_i32_16x16x64_i8(A##1, B##0, ACC[1][0], 0, 0, 0); \
    ACC[1][1] = __builtin_amdgcn_mfma_i32_16x16x64_i8(A##1, B##1, ACC[1][1], 0, 0, 0); \
    ACC[1][2] = __builtin_amdgcn_mfma_i32_16x16x64_i8(A##1, B##2, ACC[1][2], 0, 0, 0); \
    ACC[1][3] = __builtin_amdgcn_mfma_i32_16x16x64_i8(A##1, B##3, ACC[1][3], 0, 0, 0); \
    ACC[2][0] = __builtin_amdgcn_mfma_i32_16x16x64_i8(A##2, B##0, ACC[2][0], 0, 0, 0); \
    ACC[2][1] = __builtin_amdgcn_mfma_i32_16x16x64_i8(A##2, B##1, ACC[2][1], 0, 0, 0); \
    ACC[2][2] = __builtin_amdgcn_mfma_i32_16x16x64_i8(A##2, B##2, ACC[2][2], 0, 0, 0); \
    ACC[2][3] = __builtin_amdgcn_mfma_i32_16x16x64_i8(A##2, B##3, ACC[2][3], 0, 0, 0); \
    ACC[3][0] = __builtin_amdgcn_mfma_i32_16x16x64_i8(A##3, B##0, ACC[3][0], 0, 0, 0); \
    ACC[3][1] = __builtin_amdgcn_mfma_i32_16x16x64_i8(A##3, B##1, ACC[3][1], 0, 0, 0); \
    ACC[3][2] = __builtin_amdgcn_mfma_i32_16x16x64_i8(A##3, B##2, ACC[3][2], 0, 0, 0); \
    ACC[3][3] = __builtin_amdgcn_mfma_i32_16x16x64_i8(A##3, B##3, ACC[3][3], 0, 0, 0); \
    __builtin_amdgcn_s_setprio(0); } while (0)

// One K-tile from LDS slot S with B-set (BCA,BCB); stage A(TT)->SN, load B(TT)->(BNA,BNB).
#define BODY(S, SN, TT, BCA, BCB, BNA, BNB) do { \
    /* W1: read aA; stage A(next) */ \
    RDA(aA, S, 0, col0); \
    STAGEA(SN, TT); \
    BARS(); MF(acc0, aA, BCA); BARS(); \
    /* W2: read aB; load B(next) to regs */ \
    RDA(aB, S, 0, col1); \
    LOADB(BNA, BNB, TT); \
    BARS(); MF(acc0, aB, BCB); BARS(); \
    /* W3: read aC */ \
    RDA(aC, S, 1, col0); \
    BARS(); MF(acc1, aC, BCA); BARS(); \
    /* W4: read aD; drain all 12 in-flight loads (issued >=2 windows ago) */ \
    RDA(aD, S, 1, col1); \
    VMWS(0); \
    BARS(); MF(acc1, aD, BCB); BARS(); \
  } while (0)

  // prologue: stage A(0) -> slot0, load B(0) -> E set; full drain; barrier.
  STAGEA(0, 0);
  LOADB(bEA, bEB, 0);
  VMWS(0);
  BARS();

  for (int kt = 0; kt < nK - 2; kt += 2) {
    BODY(0, 1, kt + 1, bEA, bEB, bOA, bOB);
    BODY(1, 0, kt + 2, bOA, bOB, bEA, bEB);
  }
  // tile nK-2 (even, slot 0, E set), stages+loads last tile (odd -> O set)
  BODY(0, 1, nK - 1, bEA, bEB, bOA, bOB);

  // peeled last tile (slot 1, O set; nothing in flight)
  {
    RDA(aA, 1, 0, col0);
    BARS(); MF(acc0, aA, bOA); BARS();
    RDA(aB, 1, 0, col1);
    BARS(); MF(acc0, aB, bOB); BARS();
    RDA(aC, 1, 1, col0);
    BARS(); MF(acc1, aC, bOA); BARS();
    RDA(aD, 1, 1, col1);
    BARS(); MF(acc1, aD, bOB);
  }

  // ---------------- epilogue: scale + bias, store Y, per-row |y| max ----------------
  float swv[4], biv[4];
  size_t gcolv[4];
  #pragma unroll
  for (int j = 0; j < 4; ++j) {
    gcolv[j] = bcol + wc * 64 + j * 16 + l16;
    swv[j] = sw[gcolv[j]];
    biv[j] = bias[gcolv[j]];
  }
  #pragma unroll
  for (int mh = 0; mh < 2; ++mh) {
    #pragma unroll
    for (int i = 0; i < 4; ++i) {
      #pragma unroll
      for (int r = 0; r < 4; ++r) {
        const size_t grow = brow + (size_t)(wr * 128 + mh * 64 + i * 16 + g4 * 4 + r);
        const float sxr = sx[grow];
        float* yrow = Y + grow * (size_t)N;
        float rmax = 0.0f;
        #pragma unroll
        for (int j = 0; j < 4; ++j) {
          const int av = mh ? acc1[i][j][r] : acc0[i][j][r];
          const float y = (float)av * (sxr * swv[j]) + biv[j];
          yrow[gcolv[j]] = y;
          rmax = fmaxf(rmax, fabsf(y));
        }
        rmax = fmaxf(rmax, __shfl_xor(rmax, 1));
        rmax = fmaxf(rmax, __shfl_xor(rmax, 2));
        rmax = fmaxf(rmax, __shfl_xor(rmax, 4));
        rmax = fmaxf(rmax, __shfl_xor(rmax, 8));
        if (l16 == 0)
          atomicMax(&rowmax[grow], __float_as_uint(rmax));
      }
    }
  }
#undef STA
#undef STAGEA
#undef BARS
#undef VMWS
#undef RDA
#undef LOADB
#undef MF
#undef BODY
}

// ---------------- in-place per-row output fake-quant ----------------
__global__ __launch_bounds__(256) void outquant_kernel(
    float* __restrict__ Y, const unsigned int* __restrict__ rowmax, int N)
{
  const size_t row = blockIdx.x;
  const float amax = __uint_as_float(rowmax[row]);
  const float scale = fmaxf(amax, 1e-5f) * (1.0f / 127.0f);
  float* __restrict__ p = Y + row * (size_t)N;
  const int nv = N >> 2;
  for (int i = threadIdx.x; i < nv; i += 256) {
    float4 v = ((float4*)p)[i];
    v.x = rintf(v.x / scale) * scale;
    v.y = rintf(v.y / scale) * scale;
    v.z = rintf(v.z / scale) * scale;
    v.w = rintf(v.w / scale) * scale;
    ((float4*)p)[i] = v;
  }
}

extern "C" void kernel_launch(void* const* d_in, const int* in_sizes, int n_in,
                              void* d_out, int out_size, void* d_ws, size_t ws_size,
                              hipStream_t stream)
{
  const float* x = (const float*)d_in[0];   // [B,S,D_in] fp32
  const float* wgt = (const float*)d_in[1]; // [D_out,D_in] fp32
  const float* bias = (const float*)d_in[2];// [D_out] fp32
  float* out = (float*)d_out;               // [B,S,D_out] fp32

  const int N = in_sizes[2];                // D_out
  const int K = in_sizes[1] / N;            // D_in
  const int M = in_sizes[0] / K;            // B*S

  char* ws = (char*)d_ws;
  signed char* qx = (signed char*)ws;  ws += (size_t)M * K;         // i8
  signed char* qw = (signed char*)ws;  ws += (size_t)N * K;         // i8
  float* sx = (float*)ws;              ws += (size_t)M * sizeof(float);
  float* sw = (float*)ws;              ws += (size_t)N * sizeof(float);
  unsigned int* rowmax = (unsigned int*)ws;

  hipMemsetAsync(rowmax, 0, (size_t)M * sizeof(unsigned int), stream);

  if (K == 4096) {
    quant_rows4096_kernel<<<M, 256, 0, stream>>>(x, (u32*)qx, sx);
    quant_rows4096_kernel<<<N, 256, 0, stream>>>(wgt, (u32*)qw, sw);
  } else {
    quant_rows_kernel<<<M, 256, 0, stream>>>(x, (u32*)qx, sx, K);
    quant_rows_kernel<<<N, 256, 0, stream>>>(wgt, (u32*)qw, sw, K);
  }

  const int grid = (M / BM) * (N / BN);
  gemm_bt_kernel<<<grid, 512, 0, stream>>>(qx, qw, sx, sw, bias, out, rowmax, M, N, K);

  outquant_kernel<<<M, 256, 0, stream>>>(out, rowmax, N);
}

// Round 9
// 264.882 us; speedup vs baseline: 1.3075x; 1.3075x over previous
//
#include <hip/hip_runtime.h>

typedef unsigned int u32;
typedef __attribute__((ext_vector_type(4))) int i32x4;   // 16 i8 (A/B frag) or 4 i32 (C/D)

#define BM 256
#define BN 256
#define BKT 128   // K elements (i8) per K-tile: one LDS row = 128 B

__device__ __forceinline__ void gload16(const void* g, void* l) {
  __builtin_amdgcn_global_load_lds(
      (const __attribute__((address_space(1))) unsigned int*)g,
      (__attribute__((address_space(3))) unsigned int*)l, 16, 0, 0);
}

__device__ __forceinline__ u32 pack4_i8(float4 v, float scale) {
  const int a = (int)rintf(v.x / scale);
  const int b = (int)rintf(v.y / scale);
  const int c = (int)rintf(v.z / scale);
  const int d = (int)rintf(v.w / scale);
  return (u32)(a & 255) | (((u32)(b & 255)) << 8) |
         (((u32)(c & 255)) << 16) | (((u32)(d & 255)) << 24);
}

// ---------------- per-row fake-quant -> int8, single-pass (K==4096) ----------------
__global__ __launch_bounds__(256) void quant_rows4096_kernel(
    const float* __restrict__ src, u32* __restrict__ q,   // q: i8 rows packed as u32
    float* __restrict__ scales)
{
  const size_t row = blockIdx.x;
  const float4* __restrict__ p = (const float4*)(src + row * 4096);
  const int t = threadIdx.x;
  float4 v0 = p[t];
  float4 v1 = p[t + 256];
  float4 v2 = p[t + 512];
  float4 v3 = p[t + 768];
  float m = 0.0f;
  m = fmaxf(m, fmaxf(fmaxf(fabsf(v0.x), fabsf(v0.y)), fmaxf(fabsf(v0.z), fabsf(v0.w))));
  m = fmaxf(m, fmaxf(fmaxf(fabsf(v1.x), fabsf(v1.y)), fmaxf(fabsf(v1.z), fabsf(v1.w))));
  m = fmaxf(m, fmaxf(fmaxf(fabsf(v2.x), fabsf(v2.y)), fmaxf(fabsf(v2.z), fabsf(v2.w))));
  m = fmaxf(m, fmaxf(fmaxf(fabsf(v3.x), fabsf(v3.y)), fmaxf(fabsf(v3.z), fabsf(v3.w))));
  #pragma unroll
  for (int off = 32; off > 0; off >>= 1) m = fmaxf(m, __shfl_xor(m, off));
  __shared__ float wmax[4];
  if ((t & 63) == 0) wmax[t >> 6] = m;
  __syncthreads();
  m = fmaxf(fmaxf(wmax[0], wmax[1]), fmaxf(wmax[2], wmax[3]));
  const float scale = fmaxf(m, 1e-5f) * (1.0f / 127.0f);
  if (t == 0) scales[row] = scale;
  u32* __restrict__ qp = q + row * 1024;
  qp[t]       = pack4_i8(v0, scale);
  qp[t + 256] = pack4_i8(v1, scale);
  qp[t + 512] = pack4_i8(v2, scale);
  qp[t + 768] = pack4_i8(v3, scale);
}

// generic fallback (any K multiple of 4)
__global__ __launch_bounds__(256) void quant_rows_kernel(
    const float* __restrict__ src, u32* __restrict__ q,
    float* __restrict__ scales, int K)
{
  const size_t row = blockIdx.x;
  const float* __restrict__ p = src + row * (size_t)K;
  const int t = threadIdx.x;
  const int nv = K >> 2;
  float m = 0.0f;
  for (int i = t; i < nv; i += 256) {
    float4 v = ((const float4*)p)[i];
    m = fmaxf(m, fmaxf(fmaxf(fabsf(v.x), fabsf(v.y)),
                       fmaxf(fabsf(v.z), fabsf(v.w))));
  }
  #pragma unroll
  for (int off = 32; off > 0; off >>= 1) m = fmaxf(m, __shfl_xor(m, off));
  __shared__ float wmax[4];
  if ((t & 63) == 0) wmax[t >> 6] = m;
  __syncthreads();
  m = fmaxf(fmaxf(wmax[0], wmax[1]), fmaxf(wmax[2], wmax[3]));
  const float scale = fmaxf(m, 1e-5f) * (1.0f / 127.0f);
  if (t == 0) scales[row] = scale;
  u32* __restrict__ qp = q + row * ((size_t)K >> 2);
  for (int i = t; i < nv; i += 256) {
    float4 v = ((const float4*)p)[i];
    qp[i] = pack4_i8(v, scale);
  }
}

// ------- 256x256 8-wave i8 GEMM, BK=128, 2 merged windows/K-tile (4 barriers) -------
// C = Aq(MxK) * Bq(NxK)^T, i8 inputs, exact i32 accumulate via mfma_i32_16x16x64_i8.
// LDS: 2 slots x (A 256x128B + B 256x128B) = 128 KiB. Row = 128 B = 8 x 16B slots.
// Swizzle: LDS (row, slot16) holds global (row, slot16 ^ (row&7)).
// Ledger (per wave, FIFO): stage order per tile = e6[A0,A2,B0,B1,B2,B3], l2[A1,A3].
//   X1: stage8(kt+1) -> queue = l2(kt)+8 = 10; VMW(8) drains l2(kt)  (read in X2)
//   X2: queue = 8(kt+1); VMW(2) drains e6(kt+1)                      (read in next X1)
// Every read window's data has an all-waves drain + barrier before it (R6 invariant).
// 32-MFMA clusters amortize barrier cost 2x vs R6's 16.
__global__ __launch_bounds__(512, 2) void gemm_bt_kernel(
    const signed char* __restrict__ Aq, const signed char* __restrict__ Bq,
    const float* __restrict__ sx, const float* __restrict__ sw,
    const float* __restrict__ bias, float* __restrict__ Y,
    unsigned int* __restrict__ rowmax, int M, int N, int K)
{
  __shared__ signed char lds[2][2][BM * 128];   // [slot][A/B], 128 B per row

  int bid = (int)blockIdx.x;
  const int nwg = (int)gridDim.x;
  if ((nwg & 7) == 0) {                 // bijective XCD swizzle
    const int cpx = nwg >> 3;
    bid = (bid & 7) * cpx + (bid >> 3);
  }
  const int ntile = N / BN;
  const size_t brow = (size_t)(bid / ntile) * BM;
  const size_t bcol = (size_t)(bid % ntile) * BN;

  const int t = threadIdx.x;
  const int lane = t & 63;
  const int wid = t >> 6;
  const int wr = wid >> 2, wc = wid & 3;       // 2(M) x 4(N) wave grid
  const int g4 = lane >> 4, l16 = lane & 15, l7 = lane & 7;

  const int aRow = wr * 128 + l16;             // + mh*64 + i*16
  const int bRow = wc * 64 + l16;              // + j*16
  const int col0 = ((g4) ^ l7) * 16;           // kk=0 swizzled 16B slot (byte offset)
  const int col1 = ((4 + g4) ^ l7) * 16;       // kk=1

  // staging: thread covers row tr of each 64-row stripe and 16B slot ts,
  // pre-swizzled source slot so linear LDS dest ends up swizzled.
  const int tr = t >> 3, ts = t & 7;
  const int sslot = ts ^ (tr & 7);
  const signed char* srcA = Aq + (brow + tr) * (size_t)K + sslot * 16;
  const signed char* srcB = Bq + (bcol + tr) * (size_t)K + sslot * 16;
  const int dst = t * 16;                      // byte offset within 8 KiB stripe

  i32x4 acc0[4][4] = {};   // mh0 (rows wr*128 + 0..63), exact i32
  i32x4 acc1[4][4] = {};   // mh1 (rows wr*128 + 64..127)
  const int nK = K / BKT;

  i32x4 aA0, aA1, aA2, aA3;   // mh0 col0
  i32x4 aB0, aB1, aB2, aB3;   // mh0 col1
  i32x4 aC0, aC1, aC2, aC3;   // mh1 col0
  i32x4 aD0, aD1, aD2, aD3;   // mh1 col1
  i32x4 bA0, bA1, bA2, bA3;   // col0
  i32x4 bB0, bB1, bB2, bB3;   // col1

#define STA(S, R, TT) gload16(srcA + ((size_t)(R) * 64) * (size_t)K + (size_t)(TT) * BKT, \
                              &lds[S][0][(R) * 8192 + dst])
#define STB(S, R, TT) gload16(srcB + ((size_t)(R) * 64) * (size_t)K + (size_t)(TT) * BKT, \
                              &lds[S][1][(R) * 8192 + dst])
#define STAGE8(S, TT) do { \
    STA(S, 0, TT); STA(S, 2, TT); STB(S, 0, TT); STB(S, 1, TT); \
    STB(S, 2, TT); STB(S, 3, TT); STA(S, 1, TT); STA(S, 3, TT); } while (0)
#define BARS() do { asm volatile("" ::: "memory"); \
                    __builtin_amdgcn_s_barrier(); \
                    asm volatile("" ::: "memory"); } while (0)
#define VMWS(NN) asm volatile("s_waitcnt vmcnt(" #NN ")" ::: "memory")
#define RDA(P, S, MH, COL) do { \
    P##0 = *(const i32x4*)&lds[S][0][(aRow + (MH) * 64 +  0) * 128 + (COL)]; \
    P##1 = *(const i32x4*)&lds[S][0][(aRow + (MH) * 64 + 16) * 128 + (COL)]; \
    P##2 = *(const i32x4*)&lds[S][0][(aRow + (MH) * 64 + 32) * 128 + (COL)]; \
    P##3 = *(const i32x4*)&lds[S][0][(aRow + (MH) * 64 + 48) * 128 + (COL)]; } while (0)
#define RDB(P, S, COL) do { \
    P##0 = *(const i32x4*)&lds[S][1][(bRow +  0) * 128 + (COL)]; \
    P##1 = *(const i32x4*)&lds[S][1][(bRow + 16) * 128 + (COL)]; \
    P##2 = *(const i32x4*)&lds[S][1][(bRow + 32) * 128 + (COL)]; \
    P##3 = *(const i32x4*)&lds[S][1][(bRow + 48) * 128 + (COL)]; } while (0)
#define MF(ACC, A, B) do { \
    ACC[0][0] = __builtin_amdgcn_mfma_i32_16x16x64_i8(A##0, B##0, ACC[0][0], 0, 0, 0); \
    ACC[0][1] = __builtin_amdgcn_mfma_i32_16x16x64_i8(A##0, B##1, ACC[0][1], 0, 0, 0); \
    ACC[0][2] = __builtin_amdgcn_mfma_i32_16x16x64_i8(A##0, B##2, ACC[0][2], 0, 0, 0); \
    ACC[0][3] = __builtin_amdgcn_mfma_i32_16x16x64_i8(A##0, B##3, ACC[0][3], 0, 0, 0); \
    ACC[1][0] = __builtin_amdgcn_mfma_i32_16x16x64_i8(A##1, B##0, ACC[1][0], 0, 0, 0); \
    ACC[1][1] = __builtin_amdgcn_mfma_i32_16x16x64_i8(A##1, B##1, ACC[1][1], 0, 0, 0); \
    ACC[1][2] = __builtin_amdgcn_mfma_i32_16x16x64_i8(A##1, B##2, ACC[1][2], 0, 0, 0); \
    ACC[1][3] = __builtin_amdgcn_mfma_i32_16x16x64_i8(A##1, B##3, ACC[1][3], 0, 0, 0); \
    ACC[2][0] = __builtin_amdgcn_mfma_i32_16x16x64_i8(A##2, B##0, ACC[2][0], 0, 0, 0); \
    ACC[2][1] = __builtin_amdgcn_mfma_i32_16x16x64_i8(A##2, B##1, ACC[2][1], 0, 0, 0); \
    ACC[2][2] = __builtin_amdgcn_mfma_i32_16x16x64_i8(A##2, B##2, ACC[2][2], 0, 0, 0); \
    ACC[2][3] = __builtin_amdgcn_mfma_i32_16x16x64_i8(A##2, B##3, ACC[2][3], 0, 0, 0); \
    ACC[3][0] = __builtin_amdgcn_mfma_i32_16x16x64_i8(A##3, B##0, ACC[3][0], 0, 0, 0); \
    ACC[3][1] = __builtin_amdgcn_mfma_i32_16x16x64_i8(A##3, B##1, ACC[3][1], 0, 0, 0); \
    ACC[3][2] = __builtin_amdgcn_mfma_i32_16x16x64_i8(A##3, B##2, ACC[3][2], 0, 0, 0); \
    ACC[3][3] = __builtin_amdgcn_mfma_i32_16x16x64_i8(A##3, B##3, ACC[3][3], 0, 0, 0); } while (0)

// One K-tile in slot S, staging tile TS into slot SN. Two merged windows.
#define BODY(S, SN, TS) do { \
    /* X1: reads e6(this) both cols [guaranteed]; stage 8(next); drain l2(this) */ \
    RDA(aA, S, 0, col0); RDB(bA, S, col0); \
    RDA(aB, S, 0, col1); RDB(bB, S, col1); \
    STAGE8(SN, TS); \
    VMWS(8); \
    BARS(); \
    __builtin_amdgcn_s_setprio(1); \
    MF(acc0, aA, bA); MF(acc0, aB, bB); \
    __builtin_amdgcn_s_setprio(0); \
    BARS(); \
    /* X2: reads l2(this) both cols [guaranteed by X1 drain+bar]; drain e6(next) */ \
    RDA(aC, S, 1, col0); RDA(aD, S, 1, col1); \
    VMWS(2); \
    BARS(); \
    __builtin_amdgcn_s_setprio(1); \
    MF(acc1, aC, bA); MF(acc1, aD, bB); \
    __builtin_amdgcn_s_setprio(0); \
    BARS(); \
  } while (0)

  // prologue: stage tile0 -> slot0; guarantee its e6.
  STAGE8(0, 0);
  VMWS(2);                        // drain e6(t0); l2(t0) in flight
  BARS();                         // global guarantee for e6(t0)

  for (int kt = 0; kt < nK - 2; kt += 2) {
    BODY(0, 1, kt + 1);
    BODY(1, 0, kt + 2);
  }
  BODY(0, 1, nK - 1);             // tile nK-2 (slot 0), stages last tile

  // peeled last tile (slot 1, no staging). entry queue: l2(last)=2.
  {
    RDA(aA, 1, 0, col0); RDB(bA, 1, col0);
    RDA(aB, 1, 0, col1); RDB(bB, 1, col1);
    VMWS(0);                      // drain l2(last)
    BARS();
    __builtin_amdgcn_s_setprio(1);
    MF(acc0, aA, bA); MF(acc0, aB, bB);
    __builtin_amdgcn_s_setprio(0);
    BARS();
    RDA(aC, 1, 1, col0); RDA(aD, 1, 1, col1);
    BARS();
    __builtin_amdgcn_s_setprio(1);
    MF(acc1, aC, bA); MF(acc1, aD, bB);
    __builtin_amdgcn_s_setprio(0);
  }

  // ---------------- epilogue: scale + bias, store Y, per-row |y| max ----------------
  float swv[4], biv[4];
  size_t gcolv[4];
  #pragma unroll
  for (int j = 0; j < 4; ++j) {
    gcolv[j] = bcol + wc * 64 + j * 16 + l16;
    swv[j] = sw[gcolv[j]];
    biv[j] = bias[gcolv[j]];
  }
  #pragma unroll
  for (int mh = 0; mh < 2; ++mh) {
    #pragma unroll
    for (int i = 0; i < 4; ++i) {
      #pragma unroll
      for (int r = 0; r < 4; ++r) {
        const size_t grow = brow + (size_t)(wr * 128 + mh * 64 + i * 16 + g4 * 4 + r);
        const float sxr = sx[grow];
        float* yrow = Y + grow * (size_t)N;
        float rmax = 0.0f;
        #pragma unroll
        for (int j = 0; j < 4; ++j) {
          const int av = mh ? acc1[i][j][r] : acc0[i][j][r];
          const float y = (float)av * (sxr * swv[j]) + biv[j];
          yrow[gcolv[j]] = y;
          rmax = fmaxf(rmax, fabsf(y));
        }
        rmax = fmaxf(rmax, __shfl_xor(rmax, 1));
        rmax = fmaxf(rmax, __shfl_xor(rmax, 2));
        rmax = fmaxf(rmax, __shfl_xor(rmax, 4));
        rmax = fmaxf(rmax, __shfl_xor(rmax, 8));
        if (l16 == 0)
          atomicMax(&rowmax[grow], __float_as_uint(rmax));
      }
    }
  }
#undef STA
#undef STB
#undef STAGE8
#undef BARS
#undef VMWS
#undef RDA
#undef RDB
#undef MF
#undef BODY
}

// ---------------- in-place per-row output fake-quant ----------------
__global__ __launch_bounds__(256) void outquant_kernel(
    float* __restrict__ Y, const unsigned int* __restrict__ rowmax, int N)
{
  const size_t row = blockIdx.x;
  const float amax = __uint_as_float(rowmax[row]);
  const float scale = fmaxf(amax, 1e-5f) * (1.0f / 127.0f);
  float* __restrict__ p = Y + row * (size_t)N;
  const int nv = N >> 2;
  for (int i = threadIdx.x; i < nv; i += 256) {
    float4 v = ((float4*)p)[i];
    v.x = rintf(v.x / scale) * scale;
    v.y = rintf(v.y / scale) * scale;
    v.z = rintf(v.z / scale) * scale;
    v.w = rintf(v.w / scale) * scale;
    ((float4*)p)[i] = v;
  }
}

extern "C" void kernel_launch(void* const* d_in, const int* in_sizes, int n_in,
                              void* d_out, int out_size, void* d_ws, size_t ws_size,
                              hipStream_t stream)
{
  const float* x = (const float*)d_in[0];   // [B,S,D_in] fp32
  const float* wgt = (const float*)d_in[1]; // [D_out,D_in] fp32
  const float* bias = (const float*)d_in[2];// [D_out] fp32
  float* out = (float*)d_out;               // [B,S,D_out] fp32

  const int N = in_sizes[2];                // D_out
  const int K = in_sizes[1] / N;            // D_in
  const int M = in_sizes[0] / K;            // B*S

  char* ws = (char*)d_ws;
  signed char* qx = (signed char*)ws;  ws += (size_t)M * K;         // i8
  signed char* qw = (signed char*)ws;  ws += (size_t)N * K;         // i8
  float* sx = (float*)ws;              ws += (size_t)M * sizeof(float);
  float* sw = (float*)ws;              ws += (size_t)N * sizeof(float);
  unsigned int* rowmax = (unsigned int*)ws;

  hipMemsetAsync(rowmax, 0, (size_t)M * sizeof(unsigned int), stream);

  if (K == 4096) {
    quant_rows4096_kernel<<<M, 256, 0, stream>>>(x, (u32*)qx, sx);
    quant_rows4096_kernel<<<N, 256, 0, stream>>>(wgt, (u32*)qw, sw);
  } else {
    quant_rows_kernel<<<M, 256, 0, stream>>>(x, (u32*)qx, sx, K);
    quant_rows_kernel<<<N, 256, 0, stream>>>(wgt, (u32*)qw, sw, K);
  }

  const int grid = (M / BM) * (N / BN);
  gemm_bt_kernel<<<grid, 512, 0, stream>>>(qx, qw, sx, sw, bias, out, rowmax, M, N, K);

  outquant_kernel<<<M, 256, 0, stream>>>(out, rowmax, N);
}

// Round 11
// 250.940 us; speedup vs baseline: 1.3801x; 1.0556x over previous
//
#include <hip/hip_runtime.h>

typedef unsigned int u32;
typedef __attribute__((ext_vector_type(4))) int i32x4;   // 16 i8 (A/B frag) or 4 i32 (C/D)

#define BM 256
#define BN 256
#define BKT 64    // K elements (i8) per K-tile; LDS row = 64 B, paired-row swizzle

__device__ __forceinline__ void gload16(const void* g, void* l) {
  __builtin_amdgcn_global_load_lds(
      (const __attribute__((address_space(1))) unsigned int*)g,
      (__attribute__((address_space(3))) unsigned int*)l, 16, 0, 0);
}

__device__ __forceinline__ u32 pack4_i8(float4 v, float scale) {
  const int a = (int)rintf(v.x / scale);
  const int b = (int)rintf(v.y / scale);
  const int c = (int)rintf(v.z / scale);
  const int d = (int)rintf(v.w / scale);
  return (u32)(a & 255) | (((u32)(b & 255)) << 8) |
         (((u32)(c & 255)) << 16) | (((u32)(d & 255)) << 24);
}

// ---------------- per-row fake-quant -> int8, single-pass (K==4096) ----------------
__global__ __launch_bounds__(256) void quant_rows4096_kernel(
    const float* __restrict__ src, u32* __restrict__ q,   // q: i8 rows packed as u32
    float* __restrict__ scales)
{
  const size_t row = blockIdx.x;
  const float4* __restrict__ p = (const float4*)(src + row * 4096);
  const int t = threadIdx.x;
  float4 v0 = p[t];
  float4 v1 = p[t + 256];
  float4 v2 = p[t + 512];
  float4 v3 = p[t + 768];
  float m = 0.0f;
  m = fmaxf(m, fmaxf(fmaxf(fabsf(v0.x), fabsf(v0.y)), fmaxf(fabsf(v0.z), fabsf(v0.w))));
  m = fmaxf(m, fmaxf(fmaxf(fabsf(v1.x), fabsf(v1.y)), fmaxf(fabsf(v1.z), fabsf(v1.w))));
  m = fmaxf(m, fmaxf(fmaxf(fabsf(v2.x), fabsf(v2.y)), fmaxf(fabsf(v2.z), fabsf(v2.w))));
  m = fmaxf(m, fmaxf(fmaxf(fabsf(v3.x), fabsf(v3.y)), fmaxf(fabsf(v3.z), fabsf(v3.w))));
  #pragma unroll
  for (int off = 32; off > 0; off >>= 1) m = fmaxf(m, __shfl_xor(m, off));
  __shared__ float wmax[4];
  if ((t & 63) == 0) wmax[t >> 6] = m;
  __syncthreads();
  m = fmaxf(fmaxf(wmax[0], wmax[1]), fmaxf(wmax[2], wmax[3]));
  const float scale = fmaxf(m, 1e-5f) * (1.0f / 127.0f);
  if (t == 0) scales[row] = scale;
  u32* __restrict__ qp = q + row * 1024;
  qp[t]       = pack4_i8(v0, scale);
  qp[t + 256] = pack4_i8(v1, scale);
  qp[t + 512] = pack4_i8(v2, scale);
  qp[t + 768] = pack4_i8(v3, scale);
}

// generic fallback (any K multiple of 4)
__global__ __launch_bounds__(256) void quant_rows_kernel(
    const float* __restrict__ src, u32* __restrict__ q,
    float* __restrict__ scales, int K)
{
  const size_t row = blockIdx.x;
  const float* __restrict__ p = src + row * (size_t)K;
  const int t = threadIdx.x;
  const int nv = K >> 2;
  float m = 0.0f;
  for (int i = t; i < nv; i += 256) {
    float4 v = ((const float4*)p)[i];
    m = fmaxf(m, fmaxf(fmaxf(fabsf(v.x), fabsf(v.y)),
                       fmaxf(fabsf(v.z), fabsf(v.w))));
  }
  #pragma unroll
  for (int off = 32; off > 0; off >>= 1) m = fmaxf(m, __shfl_xor(m, off));
  __shared__ float wmax[4];
  if ((t & 63) == 0) wmax[t >> 6] = m;
  __syncthreads();
  m = fmaxf(fmaxf(wmax[0], wmax[1]), fmaxf(wmax[2], wmax[3]));
  const float scale = fmaxf(m, 1e-5f) * (1.0f / 127.0f);
  if (t == 0) scales[row] = scale;
  u32* __restrict__ qp = q + row * ((size_t)K >> 2);
  for (int i = t; i < nv; i += 256) {
    float4 v = ((const float4*)p)[i];
    qp[i] = pack4_i8(v, scale);
  }
}

// ------- 256x256 8-wave i8 GEMM, BK=64, QUAD-buffered LDS, 1 barrier/K-tile -------
// C = Aq(MxK) * Bq(NxK)^T, exact i32 accumulate via mfma_i32_16x16x64_i8.
// LDS: 4 slots x (A 256x64B + B 256x64B) = 128 KiB.
// Paired-row swizzle: physical 128B window = row-pair rp=r>>1; 16B slot index
//   sp = ((c>>4) + ((r&1)<<2)) ^ (rp&7).  2-way banked reads (free, m136).
// Window t: { VMWS(8); BAR; stage tile t+3 -> slot (t+3)&3; read slot t&3; 32 MFMA }.
// Safety: (a) tile-t data guarantee: every wave drains its 4 tile-t staging ops
//   (FIFO oldest of 12) via VMWS(8) BEFORE BAR_t. (b) WAR: stage targets slot
//   (t-1)&3, whose reads were consumed (register dependency via MFMA lgkm waits)
//   before each wave arrived at BAR_t; slots read in windows t,t+1,t+2 differ from
//   (t+3)&3. No timing assumptions. nK % 4 == 0, nK >= 8.
__global__ __launch_bounds__(512, 2) void gemm_bt_kernel(
    const signed char* __restrict__ Aq, const signed char* __restrict__ Bq,
    const float* __restrict__ sx, const float* __restrict__ sw,
    const float* __restrict__ bias, float* __restrict__ Y,
    unsigned int* __restrict__ rowmax, int M, int N, int K)
{
  __shared__ signed char lds[4][2][BM * 64];   // [slot][A/B], 16 KiB regions

  int bid = (int)blockIdx.x;
  const int nwg = (int)gridDim.x;
  if ((nwg & 7) == 0) {                 // bijective XCD swizzle
    const int cpx = nwg >> 3;
    bid = (bid & 7) * cpx + (bid >> 3);
  }
  const int ntile = N / BN;
  const size_t brow = (size_t)(bid / ntile) * BM;
  const size_t bcol = (size_t)(bid % ntile) * BN;

  const int t = threadIdx.x;
  const int lane = t & 63;
  const int wid = t >> 6;
  const int wr = wid >> 2, wc = wid & 3;       // 2(M) x 4(N) wave grid
  const int g4 = lane >> 4, l16 = lane & 15;

  // ds_read per-lane constants: row r = base + l16 (base % 16 == 0) ->
  // parity = l16&1, window-phase w8 = (l16>>1)&7 (bases are multiples of 16),
  // sp = (g4 + parity*4) ^ w8 ; byte = rp*128 + sp*16.
  const int parity = l16 & 1;
  const int w8 = (l16 >> 1) & 7;
  const int sp = (g4 + (parity << 2)) ^ w8;
  const int abase = (wr * 64 + (l16 >> 1)) * 128 + sp * 16;  // + mh*4096 + i*1024
  const int bbase = (wc * 32 + (l16 >> 1)) * 128 + sp * 16;  // + j*1024

  // staging: thread t -> linear LDS dst byte t*16 (+ round*8192); inverse map
  // gives the global (row, col) that belongs at (rp = t>>3 (+64), sp = t&7):
  //   q = sp ^ (rp&7) ; row = 2*rp + (q>>2) ; col = (q&3)*16.
  // round1 has rp' = rp+64 -> same q (64 & 7 == 0) -> row' = row + 128.
  const int q0 = (t & 7) ^ ((t >> 3) & 7);
  const int srow = 2 * (t >> 3) + (q0 >> 2);          // 0..127
  const int scol = (q0 & 3) * 16;
  const signed char* srcA = Aq + (brow + srow) * (size_t)K + scol;
  const signed char* srcB = Bq + (bcol + srow) * (size_t)K + scol;
  const int dstb = t * 16;

  i32x4 acc0[4][4] = {};   // mh0 (rows wr*128 + 0..63), exact i32
  i32x4 acc1[4][4] = {};   // mh1 (rows wr*128 + 64..127)
  const int nK = K / BKT;

  i32x4 aA0, aA1, aA2, aA3;   // A frags mh0
  i32x4 aC0, aC1, aC2, aC3;   // A frags mh1
  i32x4 bA0, bA1, bA2, bA3;   // B frags

#define STAGE4(S, TT) do { \
    gload16(srcA + (size_t)(TT) * 64,                      &lds[S][0][dstb]); \
    gload16(srcA + 128 * (size_t)K + (size_t)(TT) * 64,    &lds[S][0][8192 + dstb]); \
    gload16(srcB + (size_t)(TT) * 64,                      &lds[S][1][dstb]); \
    gload16(srcB + 128 * (size_t)K + (size_t)(TT) * 64,    &lds[S][1][8192 + dstb]); \
  } while (0)
#define BARS() do { asm volatile("" ::: "memory"); \
                    __builtin_amdgcn_s_barrier(); \
                    asm volatile("" ::: "memory"); } while (0)
#define VMWS(NN) asm volatile("s_waitcnt vmcnt(" #NN ")" ::: "memory")
#define RDA(P, S, MH) do { \
    P##0 = *(const i32x4*)&lds[S][0][abase + (MH) * 4096 +    0]; \
    P##1 = *(const i32x4*)&lds[S][0][abase + (MH) * 4096 + 1024]; \
    P##2 = *(const i32x4*)&lds[S][0][abase + (MH) * 4096 + 2048]; \
    P##3 = *(const i32x4*)&lds[S][0][abase + (MH) * 4096 + 3072]; } while (0)
#define RDB(P, S) do { \
    P##0 = *(const i32x4*)&lds[S][1][bbase +    0]; \
    P##1 = *(const i32x4*)&lds[S][1][bbase + 1024]; \
    P##2 = *(const i32x4*)&lds[S][1][bbase + 2048]; \
    P##3 = *(const i32x4*)&lds[S][1][bbase + 3072]; } while (0)
#define MF(ACC, A, B) do { \
    ACC[0][0] = __builtin_amdgcn_mfma_i32_16x16x64_i8(A##0, B##0, ACC[0][0], 0, 0, 0); \
    ACC[0][1] = __builtin_amdgcn_mfma_i32_16x16x64_i8(A##0, B##1, ACC[0][1], 0, 0, 0); \
    ACC[0][2] = __builtin_amdgcn_mfma_i32_16x16x64_i8(A##0, B##2, ACC[0][2], 0, 0, 0); \
    ACC[0][3] = __builtin_amdgcn_mfma_i32_16x16x64_i8(A##0, B##3, ACC[0][3], 0, 0, 0); \
    ACC[1][0] = __builtin_amdgcn_mfma_i32_16x16x64_i8(A##1, B##0, ACC[1][0], 0, 0, 0); \
    ACC[1][1] = __builtin_amdgcn_mfma_i32_16x16x64_i8(A##1, B##1, ACC[1][1], 0, 0, 0); \
    ACC[1][2] = __builtin_amdgcn_mfma_i32_16x16x64_i8(A##1, B##2, ACC[1][2], 0, 0, 0); \
    ACC[1][3] = __builtin_amdgcn_mfma_i32_16x16x64_i8(A##1, B##3, ACC[1][3], 0, 0, 0); \
    ACC[2][0] = __builtin_amdgcn_mfma_i32_16x16x64_i8(A##2, B##0, ACC[2][0], 0, 0, 0); \
    ACC[2][1] = __builtin_amdgcn_mfma_i32_16x16x64_i8(A##2, B##1, ACC[2][1], 0, 0, 0); \
    ACC[2][2] = __builtin_amdgcn_mfma_i32_16x16x64_i8(A##2, B##2, ACC[2][2], 0, 0, 0); \
    ACC[2][3] = __builtin_amdgcn_mfma_i32_16x16x64_i8(A##2, B##3, ACC[2][3], 0, 0, 0); \
    ACC[3][0] = __builtin_amdgcn_mfma_i32_16x16x64_i8(A##3, B##0, ACC[3][0], 0, 0, 0); \
    ACC[3][1] = __builtin_amdgcn_mfma_i32_16x16x64_i8(A##3, B##1, ACC[3][1], 0, 0, 0); \
    ACC[3][2] = __builtin_amdgcn_mfma_i32_16x16x64_i8(A##3, B##2, ACC[3][2], 0, 0, 0); \
    ACC[3][3] = __builtin_amdgcn_mfma_i32_16x16x64_i8(A##3, B##3, ACC[3][3], 0, 0, 0); } while (0)

// Window for tile in slot S, staging tile TT into slot (S+3)&3.
#define WIN_ST(S, TT) do { \
    VMWS(8); \
    BARS(); \
    STAGE4((S + 3) & 3, TT); \
    RDA(aA, S, 0); \
    RDB(bA, S); \
    __builtin_amdgcn_s_setprio(1); \
    MF(acc0, aA, bA); \
    __builtin_amdgcn_s_setprio(0); \
    RDA(aC, S, 1); \
    __builtin_amdgcn_s_setprio(1); \
    MF(acc1, aC, bA); \
    __builtin_amdgcn_s_setprio(0); \
  } while (0)
// Window without staging (tail), explicit drain count.
#define WIN_NS(S, VN) do { \
    VMWS(VN); \
    BARS(); \
    RDA(aA, S, 0); \
    RDB(bA, S); \
    __builtin_amdgcn_s_setprio(1); \
    MF(acc0, aA, bA); \
    __builtin_amdgcn_s_setprio(0); \
    RDA(aC, S, 1); \
    __builtin_amdgcn_s_setprio(1); \
    MF(acc1, aC, bA); \
    __builtin_amdgcn_s_setprio(0); \
  } while (0)

  // prologue: stage tiles 0,1,2 into slots 0,1,2 (12 ops in flight)
  STAGE4(0, 0);
  STAGE4(1, 1);
  STAGE4(2, 2);

  int kt = 0;
  for (; kt + 8 <= nK; kt += 4) {
    WIN_ST(0, kt + 3);
    WIN_ST(1, kt + 4);
    WIN_ST(2, kt + 5);
    WIN_ST(3, kt + 6);
  }
  // kt == nK-4 here (nK % 4 == 0). Window nK-4 stages the last tile.
  WIN_ST(0, nK - 1);
  WIN_NS(1, 8);
  WIN_NS(2, 4);
  WIN_NS(3, 0);

  // ---------------- epilogue: scale + bias, store Y, per-row |y| max ----------------
  float swv[4], biv[4];
  size_t gcolv[4];
  #pragma unroll
  for (int j = 0; j < 4; ++j) {
    gcolv[j] = bcol + wc * 64 + j * 16 + l16;
    swv[j] = sw[gcolv[j]];
    biv[j] = bias[gcolv[j]];
  }
  #pragma unroll
  for (int mh = 0; mh < 2; ++mh) {
    #pragma unroll
    for (int i = 0; i < 4; ++i) {
      #pragma unroll
      for (int r = 0; r < 4; ++r) {
        const size_t grow = brow + (size_t)(wr * 128 + mh * 64 + i * 16 + g4 * 4 + r);
        const float sxr = sx[grow];
        float* yrow = Y + grow * (size_t)N;
        float rmax = 0.0f;
        #pragma unroll
        for (int j = 0; j < 4; ++j) {
          const int av = mh ? acc1[i][j][r] : acc0[i][j][r];
          const float y = (float)av * (sxr * swv[j]) + biv[j];
          yrow[gcolv[j]] = y;
          rmax = fmaxf(rmax, fabsf(y));
        }
        rmax = fmaxf(rmax, __shfl_xor(rmax, 1));
        rmax = fmaxf(rmax, __shfl_xor(rmax, 2));
        rmax = fmaxf(rmax, __shfl_xor(rmax, 4));
        rmax = fmaxf(rmax, __shfl_xor(rmax, 8));
        if (l16 == 0)
          atomicMax(&rowmax[grow], __float_as_uint(rmax));
      }
    }
  }
#undef STAGE4
#undef BARS
#undef VMWS
#undef RDA
#undef RDB
#undef MF
#undef WIN_ST
#undef WIN_NS
}

// ---------------- in-place per-row output fake-quant ----------------
__global__ __launch_bounds__(256) void outquant_kernel(
    float* __restrict__ Y, const unsigned int* __restrict__ rowmax, int N)
{
  const size_t row = blockIdx.x;
  const float amax = __uint_as_float(rowmax[row]);
  const float scale = fmaxf(amax, 1e-5f) * (1.0f / 127.0f);
  float* __restrict__ p = Y + row * (size_t)N;
  const int nv = N >> 2;
  for (int i = threadIdx.x; i < nv; i += 256) {
    float4 v = ((float4*)p)[i];
    v.x = rintf(v.x / scale) * scale;
    v.y = rintf(v.y / scale) * scale;
    v.z = rintf(v.z / scale) * scale;
    v.w = rintf(v.w / scale) * scale;
    ((float4*)p)[i] = v;
  }
}

extern "C" void kernel_launch(void* const* d_in, const int* in_sizes, int n_in,
                              void* d_out, int out_size, void* d_ws, size_t ws_size,
                              hipStream_t stream)
{
  const float* x = (const float*)d_in[0];   // [B,S,D_in] fp32
  const float* wgt = (const float*)d_in[1]; // [D_out,D_in] fp32
  const float* bias = (const float*)d_in[2];// [D_out] fp32
  float* out = (float*)d_out;               // [B,S,D_out] fp32

  const int N = in_sizes[2];                // D_out
  const int K = in_sizes[1] / N;            // D_in
  const int M = in_sizes[0] / K;            // B*S

  char* ws = (char*)d_ws;
  signed char* qx = (signed char*)ws;  ws += (size_t)M * K;         // i8
  signed char* qw = (signed char*)ws;  ws += (size_t)N * K;         // i8
  float* sx = (float*)ws;              ws += (size_t)M * sizeof(float);
  float* sw = (float*)ws;              ws += (size_t)N * sizeof(float);
  unsigned int* rowmax = (unsigned int*)ws;

  hipMemsetAsync(rowmax, 0, (size_t)M * sizeof(unsigned int), stream);

  if (K == 4096) {
    quant_rows4096_kernel<<<M, 256, 0, stream>>>(x, (u32*)qx, sx);
    quant_rows4096_kernel<<<N, 256, 0, stream>>>(wgt, (u32*)qw, sw);
  } else {
    quant_rows_kernel<<<M, 256, 0, stream>>>(x, (u32*)qx, sx, K);
    quant_rows_kernel<<<N, 256, 0, stream>>>(wgt, (u32*)qw, sw, K);
  }

  const int grid = (M / BM) * (N / BN);
  gemm_bt_kernel<<<grid, 512, 0, stream>>>(qx, qw, sx, sw, bias, out, rowmax, M, N, K);

  outquant_kernel<<<M, 256, 0, stream>>>(out, rowmax, N);
}